// Round 6
// baseline (322.641 us; speedup 1.0000x reference)
//
#include <hip/hip_runtime.h>
#include <math.h>

typedef unsigned int u32;
typedef unsigned long long u64;

#define BB 4
#define AA 262144              // 1<<18
#define NN (BB*AA)
#define PRE 4000
#define POST 1000
#define CAP 4096
#define MASKW 64
#define NBLK 63                // ceil(4000/64)

// ---- workspace layout (bytes) ----
// ctrl + keys contiguous so ONE memset(0) covers both (key encoding makes
// zero-padding sort last; see k_compact comment).
static const size_t OFF_HIST = 0;                          // 4*4*256*4 = 16384
static const size_t OFF_PFX  = 16384;                      // u32[4]
static const size_t OFF_NEED = 16448;                      // int[4]
static const size_t OFF_KEPT = 16512;                      // int[4]
static const size_t OFF_CNTG = 16640;                      // int, stride 32 ints (128B) x4
static const size_t OFF_CNTE = 17152;                      // int, stride 32 ints (128B) x4
static const size_t CTRL_END = 17664;
static const size_t OFF_KEYS = 17664;                              // u64[4][4096] = 128K
static const size_t ZERO_END = OFF_KEYS + (size_t)BB*CAP*8;        // 148736
static const size_t OFF_MONO = ZERO_END;                           // u32[NN] = 4 MiB
static const size_t OFF_CROW = OFF_MONO + (size_t)NN*4;            // float[4][4096][8]
static const size_t OFF_NBOX = OFF_CROW + (size_t)BB*CAP*8*4;      // float[4][4096][8]
static const size_t OFF_SEL  = OFF_NBOX + (size_t)BB*CAP*8*4;      // int[4][1000] (padded 16K)
static const size_t OFF_MASK = OFF_SEL + 16384;            // u64[4][64][4000] col-major = 8 MB

// ---- radix histogram pass (8 bits per pass, MSB first) ----
__global__ void k_hist(const float* __restrict__ obj, u32* __restrict__ mono,
                       u32* __restrict__ hist, const u32* __restrict__ pfx, int pass) {
  __shared__ u32 lh[256];
  lh[threadIdx.x] = 0;
  __syncthreads();
  size_t base = (size_t)blockIdx.x * 1024;   // 1024 items per block, never crosses a batch
  int b = (int)(base >> 18);
  u32 p = pass ? pfx[b] : 0u;
  for (int k = 0; k < 4; ++k) {
    size_t g = base + threadIdx.x + (size_t)k*256;
    u32 m;
    if (pass == 0) {
      float x = obj[g];
      float e = (float)exp(-(double)x);      // correctly-rounded f32 exp
      float s = 1.0f / (1.0f + e);           // f32 sigmoid pipeline
      m = __float_as_uint(s);                // scores in (0,1): bits order == value order
      mono[g] = m;
    } else {
      m = mono[g];
    }
    u32 bin; bool ok;
    if (pass == 0)      { ok = true;            bin = m >> 24; }
    else if (pass == 1) { ok = (m >> 24) == p;  bin = (m >> 16) & 255u; }
    else if (pass == 2) { ok = (m >> 16) == p;  bin = (m >> 8)  & 255u; }
    else                { ok = (m >> 8)  == p;  bin = m & 255u; }
    if (ok) atomicAdd(&lh[bin], 1u);
  }
  __syncthreads();
  u32 v = lh[threadIdx.x];
  if (v) atomicAdd(&hist[((size_t)pass*BB + b)*256 + threadIdx.x], v);
}

__global__ void k_resolve(const u32* __restrict__ hist, u32* __restrict__ pfx,
                          int* __restrict__ need, int pass) {
  int b = threadIdx.x;
  if (b >= BB) return;
  u32 p = pass ? pfx[b] : 0u;
  int nd = pass ? need[b] : PRE;
  const u32* h = hist + ((size_t)pass*BB + b)*256;
  u32 acc = 0; int chosen = 0;
  for (int bin = 255; bin >= 0; --bin) {
    u32 c = h[bin];
    if (acc + c >= (u32)nd) { chosen = bin; nd -= (int)acc; break; }
    acc += c;
  }
  pfx[b] = (p << 8) | (u32)chosen;   // after pass 3: full 32-bit value of the 4000th score
  need[b] = nd;                      // after pass 3: how many ties at V belong in top-4000
}

// ---- compact candidates: LDS-staged, one global atomic per block per class ----
// Key encoding: (m<<32) | (AA-1-idx). Rank by DESCENDING key == score desc,
// idx asc (lax.top_k order). sigmoid > 0 so m > 0 always -> the zero-filled
// padding keys are strictly smaller than every real key and rank last.
__global__ __launch_bounds__(256) void k_compact(const u32* __restrict__ mono,
                                                 const u32* __restrict__ pfx,
                                                 int* __restrict__ cntG,
                                                 int* __restrict__ cntE,
                                                 u64* __restrict__ keys) {
  __shared__ u64 st[4096];            // G from front, ties from back
  __shared__ int nG, nE, baseG, baseE;
  int tid = threadIdx.x;
  if (tid == 0) { nG = 0; nE = 0; }
  __syncthreads();
  size_t blockBase = (size_t)blockIdx.x * 4096;
  int b = (int)(blockBase >> 18);
  u32 V = pfx[b];
  for (int k = 0; k < 16; ++k) {
    size_t g = blockBase + (size_t)k*256 + tid;
    u32 m = mono[g];
    if (m >= V) {
      u64 key = ((u64)m << 32) | (u64)(AA - 1 - (u32)(g & (AA - 1)));
      if (m > V) { int p = atomicAdd(&nG, 1); st[p] = key; }
      else       { int p = atomicAdd(&nE, 1); if (p < 512) st[4095 - p] = key; }
    }
  }
  __syncthreads();
  int ne = nE < 512 ? nE : 512;
  if (tid == 0) baseG = atomicAdd(&cntG[b*32], nG);
  if (tid == 1) baseE = atomicAdd(&cntE[b*32], ne);
  __syncthreads();
  for (int i = tid; i < nG; i += 256) {
    int p = baseG + i;
    if (p < CAP) keys[(size_t)b*CAP + p] = st[i];
  }
  for (int i = tid; i < ne; i += 256) {
    int slot = CAP - 1 - (baseE + i);
    if (slot >= 0) keys[(size_t)b*CAP + slot] = st[4095 - i];
  }
}

// ---- rank + decode fused: replaces bitonic sort + decode ----
// R5's bitonic k_sort: 4 blocks, 78 barrier rounds, 49 us at 0.65% occupancy.
// Keys are unique -> sorted position of key i == #{j: key_j > key_i}.
// 67M u64 compares total, spread over 256 one-wave blocks (1 per CU): each
// lane ranks one key via LDS broadcast reads, then decodes its box directly
// into the rank slot (kills the separate k_decode launch).
__global__ __launch_bounds__(64) void k_rank(const u64* __restrict__ keys,
                                             const float* __restrict__ reg,
                                             const float* __restrict__ anc,
                                             float* __restrict__ crow,
                                             float* __restrict__ nbox) {
  __shared__ __align__(16) u64 sk[CAP];   // 32 KB
  int b = blockIdx.y;
  const u64* kb = keys + (size_t)b*CAP;
  for (int t = threadIdx.x; t < CAP; t += 64) sk[t] = kb[t];
  __syncthreads();
  int slot = blockIdx.x*64 + threadIdx.x;
  u64 myk = sk[slot];
  int rank = 0;
  const ulonglong2* p2 = (const ulonglong2*)sk;
  #pragma unroll 8
  for (int jj = 0; jj < CAP/2; ++jj) {    // broadcast reads: conflict-free
    ulonglong2 v = p2[jj];
    rank += (int)(v.x > myk) + (int)(v.y > myk);
  }
  if (myk == 0 || rank >= PRE) return;    // padding or beyond top-4000
  u32 m = (u32)(myk >> 32);
  int idx = AA - 1 - (int)(myk & 0xFFFFFFFFull);
  float score = __uint_as_float(m);
  size_t g = ((size_t)b << 18) + (size_t)idx;
  const float* rg = reg + g*7;
  const float* an = anc + g*7;
  float xa=an[0], ya=an[1], za=an[2], wa=an[3], la=an[4], ha=an[5], ra=an[6];
  float dx=rg[0], dy=rg[1], dz=rg[2], dw=rg[3], dl=rg[4], dh=rg[5], dr=rg[6];
  float diag = sqrtf(wa*wa + la*la);
  float x = dx*diag + xa;
  float y = dy*diag + ya;
  float z = dz*ha + za;
  float w = expf(dw)*wa;
  float l = expf(dl)*la;
  float h = expf(dh)*ha;
  float r = dr + ra;
  float* cr = crow + ((size_t)b*CAP + rank)*8;
  cr[0]=x; cr[1]=y; cr[2]=z; cr[3]=w; cr[4]=l; cr[5]=h; cr[6]=r; cr[7]=score;
  float sx = fmaxf(w, 0.2f), sy = fmaxf(l, 0.2f), sz = fmaxf(h, 0.2f);
  float* nb = nbox + ((size_t)b*CAP + rank)*8;
  nb[0]=x - sx*0.5f; nb[1]=y - sy*0.5f; nb[2]=z;
  nb[3]=x + sx*0.5f; nb[4]=y + sy*0.5f; nb[5]=z + sz;
  nb[6]=sx*sy*sz;   nb[7]=0.f;
}

// ---- suppression bitmask, col-major mask[b][word c][row i] ----
__global__ __launch_bounds__(256) void k_mask(const float* __restrict__ nbox,
                                              u64* __restrict__ mask) {
  int c = blockIdx.x;            // word/column block 0..62
  int R = blockIdx.y;            // 256-row tile 0..15
  int b = blockIdx.z;
  if (c < R*4) return;           // tile fully below diagonal: words never read
  __shared__ float4 ca4[64], cb4[64];
  int t = threadIdx.x;
  int j0 = c*64;
  if (t < 64) {
    int j = j0 + t; int jc = j < PRE ? j : 0;
    const float4* p = (const float4*)(nbox + ((size_t)b*CAP + jc)*8);
    ca4[t] = p[0]; cb4[t] = p[1];
  }
  __syncthreads();
  int i = R*256 + t;
  if (i >= PRE) return;
  const float4* rp = (const float4*)(nbox + ((size_t)b*CAP + i)*8);
  float4 A = rp[0], Bv = rp[1];  // A = lo.xyz, hi.x ; Bv = hi.y, hi.z, vol, pad
  u64 bits = 0;
  #pragma unroll
  for (int jj = 0; jj < 64; ++jj) {
    float4 C = ca4[jj], D = cb4[jj];
    float d0 = fminf(A.w,  C.w) - fmaxf(A.x, C.x);
    float d1 = fminf(Bv.x, D.x) - fmaxf(A.y, C.y);
    float d2 = fminf(Bv.y, D.y) - fmaxf(A.z, C.z);
    float inter = fmaxf(d0, 0.f) * fmaxf(d1, 0.f) * fmaxf(d2, 0.f);
    float uni = Bv.z + D.z - inter;
    if (inter > 0.3f * uni) bits |= (1ull << jj);
  }
  int vcols = PRE - j0;                                  // >= 32 for c <= 62
  if (vcols < 64) bits &= ((1ull << vcols) - 1ull);      // clear cols >= PRE
  if (j0 <= i) {                                          // clear cols j <= i
    int d = i - j0;
    if (d >= 63) bits = 0;
    else bits &= ~((2ull << d) - 1ull);
  }
  mask[((size_t)b*MASKW + c)*PRE + i] = bits;
}

// ---- block-sequential greedy NMS reduce: one wave per batch, SINGLE buffer ----
// (R4 lesson: two 64-u64 buffers = 256 VGPR -> spill; one fits at ~150.)
__global__ __launch_bounds__(64) void k_reduce(const u64* __restrict__ mask,
                                               int* __restrict__ sel,
                                               int* __restrict__ kept) {
  int b = blockIdx.x, lane = threadIdx.x;
  const u64* col = mask + ((size_t)b*MASKW + lane)*PRE;   // this lane's word-column
  u64 removed = 0;
  int kc = 0;
  for (int q = 0; q < NBLK; ++q) {
    u64 buf[64];
    bool act = lane >= q;        // words < q of these rows were never written
    if (q < NBLK - 1) {          // rows q*64 .. q*64+63 all < PRE
      const ulonglong2* p = (const ulonglong2*)(col + q*64);
      #pragma unroll
      for (int jj = 0; jj < 32; ++jj) {
        ulonglong2 v; v.x = 0; v.y = 0;
        if (act) v = p[jj];
        buf[2*jj] = v.x; buf[2*jj+1] = v.y;
      }
    } else {                     // last block: guard rows >= PRE
      #pragma unroll
      for (int jj = 0; jj < 64; ++jj) {
        int row = q*64 + jj;
        u64 v = 0;
        if (act && row < PRE) v = col[row];
        buf[jj] = v;
      }
    }
    int nv = PRE - q*64; if (nv > 64) nv = 64;
    u64 cur = removed, km = 0;
    #pragma unroll
    for (int jj = 0; jj < 64; ++jj) {
      if (((cur >> jj) & 1ull) == 0ull) { km |= (1ull << jj); cur |= buf[jj]; }
    }
    u64 kmw = __shfl(km, q, 64);
    if (nv < 64) kmw &= ((1ull << nv) - 1ull);
    #pragma unroll
    for (int jj = 0; jj < 64; ++jj) {
      if ((kmw >> jj) & 1ull) removed |= buf[jj];
    }
    bool mine = (kmw >> lane) & 1ull;
    int pos = kc + (int)__popcll(kmw & ((1ull << lane) - 1ull));
    if (mine && pos < POST) sel[b*POST + pos] = q*64 + lane;
    kc += (int)__popcll(kmw);
    if (kc >= POST) break;
  }
  if (lane == 0) kept[b] = kc < POST ? kc : POST;
}

// ---- gather output rows; zero-fill invalid ranks (matches boxes[sel]*valid) ----
__global__ void k_out(const float* __restrict__ crow, const int* __restrict__ sel,
                      const int* __restrict__ kept, float* __restrict__ out) {
  int t = blockIdx.x*256 + threadIdx.x;
  if (t >= BB*POST) return;
  int b = t / POST, r = t - b*POST;
  float4 o0 = make_float4(0.f,0.f,0.f,0.f), o1 = o0;
  if (r < kept[b]) {
    int i = sel[b*POST + r];
    const float4* p = (const float4*)(crow + ((size_t)b*CAP + i)*8);
    o0 = p[0]; o1 = p[1];
  }
  float4* q = (float4*)(out + (size_t)t*8);
  q[0] = o0; q[1] = o1;
}

extern "C" void kernel_launch(void* const* d_in, const int* in_sizes, int n_in,
                              void* d_out, int out_size, void* d_ws, size_t ws_size,
                              hipStream_t stream) {
  const float* obj = (const float*)d_in[0];   // (N,)
  const float* reg = (const float*)d_in[1];   // (N,7)
  const float* anc = (const float*)d_in[2];   // (N,7)
  float* out = (float*)d_out;                 // (4,1000,8)
  char* ws = (char*)d_ws;

  u32*  hist = (u32*)(ws + OFF_HIST);
  u32*  pfx  = (u32*)(ws + OFF_PFX);
  int*  need = (int*)(ws + OFF_NEED);
  int*  kept = (int*)(ws + OFF_KEPT);
  int*  cntG = (int*)(ws + OFF_CNTG);
  int*  cntE = (int*)(ws + OFF_CNTE);
  u64*  keys = (u64*)(ws + OFF_KEYS);
  u32*  mono = (u32*)(ws + OFF_MONO);
  float* crow = (float*)(ws + OFF_CROW);
  float* nbox = (float*)(ws + OFF_NBOX);
  int*  sel  = (int*)(ws + OFF_SEL);
  u64*  mask = (u64*)(ws + OFF_MASK);

  hipMemsetAsync(ws, 0, ZERO_END, stream);   // hists + counters + key padding

  for (int pass = 0; pass < 4; ++pass) {
    k_hist<<<NN/1024, 256, 0, stream>>>(obj, mono, hist, pfx, pass);
    k_resolve<<<1, 64, 0, stream>>>(hist, pfx, need, pass);
  }
  k_compact<<<NN/4096, 256, 0, stream>>>(mono, pfx, cntG, cntE, keys);
  k_rank<<<dim3(CAP/64, BB), 64, 0, stream>>>(keys, reg, anc, crow, nbox);
  k_mask<<<dim3(NBLK, 16, BB), 256, 0, stream>>>(nbox, mask);
  k_reduce<<<BB, 64, 0, stream>>>(mask, sel, kept);
  k_out<<<(BB*POST + 255)/256, 256, 0, stream>>>(crow, sel, kept, out);
}